// Round 15
// baseline (57.970 us; speedup 1.0000x reference)
//
#include <hip/hip_runtime.h>
#include <hip/hip_bf16.h>

typedef unsigned short ushortT;
typedef __attribute__((ext_vector_type(8))) short bf16x8;
typedef __attribute__((ext_vector_type(4))) float f32x4;
typedef __attribute__((ext_vector_type(2))) float f32x2;

#define N_NODES 384
#define KNBR 60
#define SUBK 20
#define NEDGE (N_NODES * KNBR)            // 23040
#define EPSC 1e-8f
#define INV_SQRT_CZ 0.08838834764831845f  // 1/sqrt(128), folded into Wp1 q-cols
#define MU_STEP (20.0f / 63.0f)
#define INV_MU_STEP (63.0f / 20.0f)
#define INV_SIGMA 3.2f
#define QKV_BLOCKS 360                    // 64 rows each
#define BIAS_BLOCKS 900                   // 512 pairs each

__device__ __forceinline__ float bflo(unsigned int u) { return __uint_as_float(u << 16); }
__device__ __forceinline__ float bfhi(unsigned int u) { return __uint_as_float(u & 0xffff0000u); }
__device__ __forceinline__ f32x2 bfpair(unsigned int u) {
  f32x2 r; r.x = bflo(u); r.y = bfhi(u); return r;
}
__device__ __forceinline__ ushortT f2bu(float v) {  // f32 -> bf16 bits, RNE
  union { float f; unsigned int u; } c;
  c.f = v;
  return (ushortT)((c.u + 0x7fffu + ((c.u >> 16) & 1u)) >> 16);
}
__device__ __forceinline__ unsigned int pack2bf(float x, float y) {
  return (unsigned int)f2bu(x) | ((unsigned int)f2bu(y) << 16);
}
__device__ __forceinline__ ushortT f2h(float x) {
  _Float16 h = (_Float16)x;
  return __builtin_bit_cast(ushortT, h);
}
__device__ __forceinline__ float h2f(ushortT u) {
  return (float)__builtin_bit_cast(_Float16, u);
}

// Fused prep: blocks 0..95 = gate projection; blocks 96..351 = weight packing
// (q-columns pre-scaled by 1/sqrt(c_z)) + bias concat.
__global__ __launch_bounds__(256) void prep_kernel(
    const float* __restrict__ nf, const float* __restrict__ Wg, float* __restrict__ g,
    const float* __restrict__ Wqk, const float* __restrict__ bqk,
    const float* __restrict__ Wv, const float* __restrict__ bv,
    const float* __restrict__ Wout,
    ushortT* __restrict__ Wp1, ushortT* __restrict__ Wp2, float* __restrict__ bc) {
  int b = blockIdx.x, tid = threadIdx.x;
  if (b < 96) {
    int n = b * 4 + (tid >> 6), t = tid & 63;
    float a = nf[n * 128 + t];
    float bb = nf[n * 128 + 64 + t];
    float acc[8];
#pragma unroll
    for (int h = 0; h < 4; ++h) {
      acc[h]     = a * Wg[t * 4 + h]         + bb * Wg[(t + 64) * 4 + h];
      acc[4 + h] = a * Wg[(128 + t) * 4 + h] + bb * Wg[(192 + t) * 4 + h];
    }
#pragma unroll
    for (int i = 0; i < 8; ++i)
#pragma unroll
      for (int off = 32; off >= 1; off >>= 1) acc[i] += __shfl_xor(acc[i], off, 64);
    if (t == 0) {
#pragma unroll
      for (int i = 0; i < 8; ++i) g[n * 8 + i] = acc[i];
    }
  } else {
    int i = (b - 96) * 256 + tid;  // 65536 total
    if (i < 49152) {
      int j = i & 7, l = (i >> 3) & 63, t = (i >> 9) & 3;
      int nt = (i >> 11) % 12, ny = (i >> 11) / 12;
      int nn = ny * 192 + nt * 16 + (l & 15);
      int k = t * 32 + (l >> 4) * 8 + j;
      float v = (nn < 256) ? Wqk[k * 256 + nn] : Wv[k * 128 + (nn - 256)];
      if (nn < 128) v *= INV_SQRT_CZ;   // q columns pre-scaled
      Wp1[i] = f2bu(v);
    } else {
      int i2 = i - 49152;  // 16384
      int j = i2 & 7, l = (i2 >> 3) & 63, t = (i2 >> 9) & 3, nt = (i2 >> 11);
      int nn = nt * 16 + (l & 15);
      int k = t * 32 + (l >> 4) * 8 + j;
      Wp2[i2] = f2bu(Wout[k * 128 + nn]);
    }
    if (i < 384) {
      float v = (i < 256) ? bqk[i] : bv[i - 256];
      if (i < 128) v *= INV_SQRT_CZ;
      bc[i] = v;
    }
  }
}

// K2: blocks 0..359 = qkv projection (64 rows each, MFMA, weights direct from
// global); blocks 360..1259 = bias pairs (one (e,s) per thread). The two
// populations co-reside on CUs -> load-latency and trans-latency interleave.
__global__ __launch_bounds__(512) void proj_bias_kernel(
    const float* __restrict__ ef, const ushortT* __restrict__ Wp1,
    const float* __restrict__ bc, const int* __restrict__ ei,
    const int* __restrict__ si, const float* __restrict__ nt,
    const float* __restrict__ g, const float* __restrict__ W_db,
    const float* __restrict__ b_db, const float* __restrict__ b_gate,
    ushortT* __restrict__ qws, ushortT* __restrict__ kvws,
    ushortT* __restrict__ biasws) {
  int b = blockIdx.x, tid = threadIdx.x;
  if (b < QKV_BLOCKS) {
    int w = tid >> 6, l = tid & 63;
    int lr = l & 15, lc = l >> 4;
    int row = b * 64 + (w & 3) * 16 + lr;
    int Tbase = (tid >> 8) * 12;
    bf16x8 afrag[4];
#pragma unroll
    for (int t = 0; t < 4; ++t) {
      const float* ap = ef + (size_t)row * 128 + t * 32 + lc * 8;
      float4 lo = *(const float4*)ap;
      float4 hi = *(const float4*)(ap + 4);
      bf16x8 a;
      a[0] = (short)f2bu(lo.x); a[1] = (short)f2bu(lo.y);
      a[2] = (short)f2bu(lo.z); a[3] = (short)f2bu(lo.w);
      a[4] = (short)f2bu(hi.x); a[5] = (short)f2bu(hi.y);
      a[6] = (short)f2bu(hi.z); a[7] = (short)f2bu(hi.w);
      afrag[t] = a;
    }
#pragma unroll
    for (int Ti = 0; Ti < 12; ++Ti) {
      int T = Tbase + Ti;
      f32x4 acc = {0.f, 0.f, 0.f, 0.f};
#pragma unroll
      for (int t = 0; t < 4; ++t) {
        bf16x8 bfrag = *(const bf16x8*)(Wp1 + ((T * 4 + t) * 64 + l) * 8);
        acc = __builtin_amdgcn_mfma_f32_16x16x32_bf16(bfrag, afrag[t], acc, 0, 0, 0);
      }
      int col0 = T * 16 + lc * 4;
      float4 bi = *(const float4*)(bc + col0);
      uint2 o;
      o.x = pack2bf(acc[0] + bi.x, acc[1] + bi.y);
      o.y = pack2bf(acc[2] + bi.z, acc[3] + bi.w);
      if (T < 8) {
        *(uint2*)(qws + (size_t)row * 128 + col0) = o;        // q (pre-scaled)
      } else {
        *(uint2*)(kvws + (size_t)row * 256 + (col0 - 128)) = o;  // k|v row-major
      }
    }
  } else {
    int p = (b - QKV_BLOCKS) * 512 + tid;  // 0..460799
    int e = p / SUBK, s = p - e * SUBK;
    int n = e / KNBR;
    int j = si[p];
    int dk = ei[e];
    int dj = ei[n * KNBR + j];
    float dx = nt[dk * 3 + 0] - nt[dj * 3 + 0] + EPSC;
    float dy = nt[dk * 3 + 1] - nt[dj * 3 + 1] + EPSC;
    float dz = nt[dk * 3 + 2] - nt[dj * 3 + 2] + EPSC;
    float dist = sqrtf(dx * dx + dy * dy + dz * dz);
    int r0 = (int)(dist * INV_MU_STEP + 0.5f);
    int rlo = max(r0 - 4, 0), rhi = min(r0 + 4, 63);
    float a0 = 0.f, a1 = 0.f, a2 = 0.f, a3 = 0.f;
    for (int r = rlo; r <= rhi; ++r) {
      float t = (dist - r * MU_STEP) * INV_SIGMA;
      float eexp = __expf(-t * t);
      float4 wv = ((const float4*)W_db)[r];
      a0 += eexp * wv.x; a1 += eexp * wv.y; a2 += eexp * wv.z; a3 += eexp * wv.w;
    }
    float4 bgv = *(const float4*)b_gate;
    float4 bdbv = *(const float4*)b_db;
    float4 gk = *(const float4*)(g + dk * 8);       // g1(dk)
    float4 gj = *(const float4*)(g + dj * 8 + 4);   // g2(dj)
    float g1 = gk.x + gj.x + bgv.x;
    float g2 = gk.y + gj.y + bgv.y;
    float g3 = gk.z + gj.z + bgv.z;
    float g4 = gk.w + gj.w + bgv.w;
    uint2 o;
    o.x = (unsigned int)f2h((a0 + bdbv.x) / (1.0f + __expf(-g1))) |
          ((unsigned int)f2h((a1 + bdbv.y) / (1.0f + __expf(-g2))) << 16);
    o.y = (unsigned int)f2h((a2 + bdbv.z) / (1.0f + __expf(-g3))) |
          ((unsigned int)f2h((a3 + bdbv.w) / (1.0f + __expf(-g4))) << 16);
    *(uint2*)(biasws + (size_t)p * 4) = o;
  }
}

// K3: edge-parallel attention + in-block out projection. 32 edges/block,
// 8 threads/edge = (h, dh). All K/V/q/bias reads via L2 (per-edge-octet reads
// are 256B contiguous since the octet shares j). upd staged in LDS; one barrier;
// MFMA out-proj with Wp2 direct from global.
__global__ __launch_bounds__(256) void attn_out_kernel(
    const ushortT* __restrict__ qws, const ushortT* __restrict__ kvws,
    const ushortT* __restrict__ biasws, const int* __restrict__ si,
    const ushortT* __restrict__ Wp2, const float* __restrict__ bout,
    float* __restrict__ outp) {
  __shared__ __align__(16) ushortT updb[32 * 136];  // 8704 B
  int b = blockIdx.x, tid = threadIdx.x;
  int le = tid >> 3, h = (tid >> 1) & 3, dh = tid & 1;
  int e = b * 32 + le;
  int n = e / KNBR;
  int jbase = n * KNBR;

  f32x2 qv0, qv1, qv2, qv3, qv4, qv5, qv6, qv7;
  {
    const ushortT* qp = qws + (size_t)e * 128 + h * 32 + dh * 16;
    uint4 u0 = *(const uint4*)qp;
    uint4 u1 = *(const uint4*)(qp + 8);
    qv0 = bfpair(u0.x); qv1 = bfpair(u0.y); qv2 = bfpair(u0.z); qv3 = bfpair(u0.w);
    qv4 = bfpair(u1.x); qv5 = bfpair(u1.y); qv6 = bfpair(u1.z); qv7 = bfpair(u1.w);
  }
  const int* sip = si + (size_t)e * SUBK;
  const ushortT* bp = biasws + (size_t)e * (SUBK * 4);
  float den = 0.f;
  f32x2 va0 = {0.f, 0.f}, va1 = {0.f, 0.f}, va2 = {0.f, 0.f}, va3 = {0.f, 0.f};
  f32x2 va4 = {0.f, 0.f}, va5 = {0.f, 0.f}, va6 = {0.f, 0.f}, va7 = {0.f, 0.f};
#pragma unroll
  for (int s = 0; s < SUBK; ++s) {
    int j = sip[s];
    const ushortT* kr = kvws + (size_t)(jbase + j) * 256 + h * 32 + dh * 16;
    uint4 k0 = *(const uint4*)kr;
    uint4 k1 = *(const uint4*)(kr + 8);
    f32x2 dacc = qv0 * bfpair(k0.x);
    dacc += qv1 * bfpair(k0.y);
    dacc += qv2 * bfpair(k0.z);
    dacc += qv3 * bfpair(k0.w);
    dacc += qv4 * bfpair(k1.x);
    dacc += qv5 * bfpair(k1.y);
    dacc += qv6 * bfpair(k1.z);
    dacc += qv7 * bfpair(k1.w);
    float dot = dacc.x + dacc.y;
    dot += __shfl_xor(dot, 1);
    float p = __expf(dot + h2f(bp[s * 4 + h]));
    den += p;
    const ushortT* vr = kr + 128;
    uint4 w0 = *(const uint4*)vr;
    uint4 w1 = *(const uint4*)(vr + 8);
    f32x2 pp = {p, p};
    va0 += pp * bfpair(w0.x);
    va1 += pp * bfpair(w0.y);
    va2 += pp * bfpair(w0.z);
    va3 += pp * bfpair(w0.w);
    va4 += pp * bfpair(w1.x);
    va5 += pp * bfpair(w1.y);
    va6 += pp * bfpair(w1.z);
    va7 += pp * bfpair(w1.w);
  }
  float inv = 1.0f / den;
  {
    uint4 o;
    o.x = pack2bf(va0.x * inv, va0.y * inv);
    o.y = pack2bf(va1.x * inv, va1.y * inv);
    o.z = pack2bf(va2.x * inv, va2.y * inv);
    o.w = pack2bf(va3.x * inv, va3.y * inv);
    *(uint4*)(updb + le * 136 + h * 32 + dh * 16) = o;
    uint4 o2;
    o2.x = pack2bf(va4.x * inv, va4.y * inv);
    o2.y = pack2bf(va5.x * inv, va5.y * inv);
    o2.z = pack2bf(va6.x * inv, va6.y * inv);
    o2.w = pack2bf(va7.x * inv, va7.y * inv);
    *(uint4*)(updb + le * 136 + h * 32 + dh * 16 + 8) = o2;
  }
  __syncthreads();

  // out projection: wave w -> rows (w&1)*16+lr, col-tiles (w>>1)*4 .. +3
  int w = tid >> 6, l = tid & 63, lr = l & 15, lc = l >> 4;
  int lrow = (w & 1) * 16 + lr;          // 0..31
  bf16x8 af2[4];
#pragma unroll
  for (int t = 0; t < 4; ++t)
    af2[t] = *(const bf16x8*)(updb + lrow * 136 + t * 32 + lc * 8);
#pragma unroll
  for (int Ti = 0; Ti < 4; ++Ti) {
    int T = (w >> 1) * 4 + Ti;
    f32x4 acc = {0.f, 0.f, 0.f, 0.f};
#pragma unroll
    for (int t = 0; t < 4; ++t) {
      bf16x8 bfrag = *(const bf16x8*)(Wp2 + ((T * 4 + t) * 64 + l) * 8);
      acc = __builtin_amdgcn_mfma_f32_16x16x32_bf16(bfrag, af2[t], acc, 0, 0, 0);
    }
    int col0 = T * 16 + lc * 4;
    float4 bi = *(const float4*)(bout + col0);
    float4 o;
    o.x = acc[0] + bi.x; o.y = acc[1] + bi.y;
    o.z = acc[2] + bi.z; o.w = acc[3] + bi.w;
    *(float4*)(outp + (size_t)(b * 32 + lrow) * 128 + col0) = o;
  }
}

extern "C" void kernel_launch(void* const* d_in, const int* in_sizes, int n_in, void* d_out,
                              int out_size, void* d_ws, size_t ws_size, hipStream_t stream) {
  const float* nf  = (const float*)d_in[0];
  const float* nt  = (const float*)d_in[1];
  const float* ef  = (const float*)d_in[2];
  const int*   ei  = (const int*)d_in[3];
  const int*   si  = (const int*)d_in[4];
  const float* Wg  = (const float*)d_in[5];
  const float* bg  = (const float*)d_in[6];
  const float* Wdb = (const float*)d_in[7];
  const float* bdb = (const float*)d_in[8];
  const float* Wqk = (const float*)d_in[9];
  const float* bqk = (const float*)d_in[10];
  const float* Wv  = (const float*)d_in[11];
  const float* bv  = (const float*)d_in[12];
  const float* Wout = (const float*)d_in[13];
  const float* bout = (const float*)d_in[14];
  float* out = (float*)d_out;  // f32 output

  float* g       = (float*)d_ws;                    // 3072 f32
  float* bc      = g + 3072;                        // 384 f32
  ushortT* Wp1   = (ushortT*)(bc + 384);            // 49152 bf16
  ushortT* Wp2   = Wp1 + 49152;                     // 16384 bf16
  ushortT* qws   = Wp2 + 16384;                     // NEDGE*128 bf16
  ushortT* kvws  = qws + (size_t)NEDGE * 128;       // NEDGE*256 bf16
  ushortT* biasws = kvws + (size_t)NEDGE * 256;     // NEDGE*80 f16

  prep_kernel<<<dim3(352), dim3(256), 0, stream>>>(nf, Wg, g, Wqk, bqk, Wv, bv, Wout,
                                                   Wp1, Wp2, bc);
  proj_bias_kernel<<<dim3(QKV_BLOCKS + BIAS_BLOCKS), dim3(512), 0, stream>>>(
      ef, Wp1, bc, ei, si, nt, g, Wdb, bdb, bg, qws, kvws, biasws);
  attn_out_kernel<<<dim3(NEDGE / 32), dim3(256), 0, stream>>>(qws, kvws, biasws, si, Wp2,
                                                              bout, out);
}

// Round 16
// 40.233 us; speedup vs baseline: 1.4408x; 1.4408x over previous
//
#include <hip/hip_runtime.h>
#include <hip/hip_bf16.h>

typedef unsigned short ushortT;
typedef __attribute__((ext_vector_type(8))) short bf16x8;
typedef __attribute__((ext_vector_type(4))) float f32x4;
typedef __attribute__((ext_vector_type(2))) float f32x2;

#define N_NODES 384
#define KNBR 60
#define SUBK 20
#define NEDGE (N_NODES * KNBR)
#define EPSC 1e-8f
#define INV_SQRT_CZ 0.08838834764831845f   // 1/sqrt(128), folded into Wp1 q-cols
#define MU_STEP (20.0f / 63.0f)
#define INV_MU_STEP (63.0f / 20.0f)
#define INV_SIGMA 3.2f

__device__ __forceinline__ float bflo(unsigned int u) { return __uint_as_float(u << 16); }
__device__ __forceinline__ float bfhi(unsigned int u) { return __uint_as_float(u & 0xffff0000u); }
__device__ __forceinline__ f32x2 bfpair(unsigned int u) {
  f32x2 r; r.x = bflo(u); r.y = bfhi(u); return r;
}
__device__ __forceinline__ ushortT f2bu(float v) {  // f32 -> bf16 bits, RNE
  union { float f; unsigned int u; } c;
  c.f = v;
  return (ushortT)((c.u + 0x7fffu + ((c.u >> 16) & 1u)) >> 16);
}
__device__ __forceinline__ unsigned int pack2bf(float x, float y) {
  return (unsigned int)f2bu(x) | ((unsigned int)f2bu(y) << 16);
}
__device__ __forceinline__ ushortT f2h(float x) {
  _Float16 h = (_Float16)x;
  return __builtin_bit_cast(ushortT, h);
}
__device__ __forceinline__ float h2f(ushortT u) {
  return (float)__builtin_bit_cast(_Float16, u);
}

// Fused prep: blocks 0..95 = gate projection; blocks 96..351 = weight packing
// (q-columns pre-scaled by 1/sqrt(c_z)) + bias concat.
__global__ __launch_bounds__(256) void prep_kernel(
    const float* __restrict__ nf, const float* __restrict__ Wg, float* __restrict__ g,
    const float* __restrict__ Wqk, const float* __restrict__ bqk,
    const float* __restrict__ Wv, const float* __restrict__ bv,
    const float* __restrict__ Wout,
    ushortT* __restrict__ Wp1, ushortT* __restrict__ Wp2, float* __restrict__ bc) {
  int b = blockIdx.x, tid = threadIdx.x;
  if (b < 96) {
    int n = b * 4 + (tid >> 6), t = tid & 63;
    float a = nf[n * 128 + t];
    float bb = nf[n * 128 + 64 + t];
    float acc[8];
#pragma unroll
    for (int h = 0; h < 4; ++h) {
      acc[h]     = a * Wg[t * 4 + h]         + bb * Wg[(t + 64) * 4 + h];
      acc[4 + h] = a * Wg[(128 + t) * 4 + h] + bb * Wg[(192 + t) * 4 + h];
    }
#pragma unroll
    for (int i = 0; i < 8; ++i)
#pragma unroll
      for (int off = 32; off >= 1; off >>= 1) acc[i] += __shfl_xor(acc[i], off, 64);
    if (t == 0) {
#pragma unroll
      for (int i = 0; i < 8; ++i) g[n * 8 + i] = acc[i];
    }
  } else {
    int i = (b - 96) * 256 + tid;  // 65536 total
    if (i < 49152) {
      int j = i & 7, l = (i >> 3) & 63, t = (i >> 9) & 3;
      int nt = (i >> 11) % 12, ny = (i >> 11) / 12;
      int nn = ny * 192 + nt * 16 + (l & 15);
      int k = t * 32 + (l >> 4) * 8 + j;
      float v = (nn < 256) ? Wqk[k * 256 + nn] : Wv[k * 128 + (nn - 256)];
      if (nn < 128) v *= INV_SQRT_CZ;   // q columns pre-scaled
      Wp1[i] = f2bu(v);
    } else {
      int i2 = i - 49152;  // 16384
      int j = i2 & 7, l = (i2 >> 3) & 63, t = (i2 >> 9) & 3, nt = (i2 >> 11);
      int nn = nt * 16 + (l & 15);
      int k = t * 32 + (l >> 4) * 8 + j;
      Wp2[i2] = f2bu(Wout[k * 128 + nn]);
    }
    if (i < 384) {
      float v = (i < 256) ? bqk[i] : bv[i - 256];
      if (i < 128) v *= INV_SQRT_CZ;
      bc[i] = v;
    }
  }
}

// One block per node, 512 threads (8 waves). Phase 1: each wave owns 2 row-sets
// x 6 col-tiles -> one B-fragment load feeds 8 MFMAs (2x fewer L2 loads, 2-wide
// MFMA ILP). Phase 4 restructured the same way (2 row-sets x 2 tiles). Phase 2
// gathers from global; kvb c-major conflict-free; single-pass packed softmax.
__global__ __launch_bounds__(512, 4) void fused_kernel(
    const float* __restrict__ ef, const ushortT* __restrict__ Wp1,
    const ushortT* __restrict__ Wp2, const float* __restrict__ bc,
    const float* __restrict__ bout, const float* __restrict__ g,
    const float* __restrict__ node_trans, const int* __restrict__ edge_index,
    const int* __restrict__ sub_idx, const float* __restrict__ W_db,
    const float* __restrict__ b_db, const float* __restrict__ b_gate,
    float* __restrict__ outp) {
  __shared__ __align__(16) ushortT kvb[KNBR * 256];     // 30720 B
  __shared__ __align__(16) ushortT updq[64 * 136];      // 17408 B (q then upd)
  __shared__ __align__(16) ushortT biasb[KNBR * SUBK * 4];  // 9600 B, f16
  __shared__ ushortT sub_lds[KNBR * SUBK];              // 2400 B

  int n = blockIdx.x, tid = threadIdx.x;
  int e0 = n * KNBR;
  int w = tid >> 6, l = tid & 63;
  int lr = l & 15, lc = l >> 4;
  int rh = w & 1;                        // row half (0: rows 0-31, 1: rows 32-63)
  int tg = w >> 1;                       // tile group 0..3

  // ---- A fragments: 2 row-sets per wave ----
  bf16x8 afr[2][4];
#pragma unroll
  for (int rs = 0; rs < 2; ++rs) {
    int row = rh * 32 + rs * 16 + lr;
    int rowc = min(row, KNBR - 1);
#pragma unroll
    for (int t = 0; t < 4; ++t) {
      const float* ap = ef + (size_t)(e0 + rowc) * 128 + t * 32 + lc * 8;
      float4 lo = *(const float4*)ap;
      float4 hi = *(const float4*)(ap + 4);
      bf16x8 a;
      a[0] = (short)f2bu(lo.x); a[1] = (short)f2bu(lo.y);
      a[2] = (short)f2bu(lo.z); a[3] = (short)f2bu(lo.w);
      a[4] = (short)f2bu(hi.x); a[5] = (short)f2bu(hi.y);
      a[6] = (short)f2bu(hi.z); a[7] = (short)f2bu(hi.w);
      afr[rs][t] = a;
    }
  }

  // ---- phase 1: qkv projection, 6 tiles/wave x 2 row-sets ----
#pragma unroll
  for (int i = 0; i < 6; ++i) {
    int T = tg * 6 + i;
    bf16x8 bfrag[4];
#pragma unroll
    for (int t = 0; t < 4; ++t)
      bfrag[t] = *(const bf16x8*)(Wp1 + ((T * 4 + t) * 64 + l) * 8);
    int col0 = T * 16 + lc * 4;
    float4 bi = *(const float4*)(bc + col0);
#pragma unroll
    for (int rs = 0; rs < 2; ++rs) {
      f32x4 acc = {0.f, 0.f, 0.f, 0.f};
#pragma unroll
      for (int t = 0; t < 4; ++t)
        acc = __builtin_amdgcn_mfma_f32_16x16x32_bf16(bfrag[t], afr[rs][t], acc, 0, 0, 0);
      int row = rh * 32 + rs * 16 + lr;
      uint2 o;
      o.x = pack2bf(acc[0] + bi.x, acc[1] + bi.y);
      o.y = pack2bf(acc[2] + bi.z, acc[3] + bi.w);
      if (T < 8) {  // q (pre-scaled) -> updq
        *(uint2*)(updq + row * 136 + col0) = o;
      } else if (row < KNBR) {  // k,v -> kvb (c-major, swizzled)
        int colk = col0 - 128;                  // 0..255
        int base_b = (colk & 128) << 1;         // 0 (K) or 256 (V)
        int d = colk & 127;
        int inner = ((d >> 3) & 1) * 128 + (((d >> 4) * 16) ^ ((row & 7) << 4)) + (d & 7) * 2;
        *(uint2*)((char*)kvb + row * 512 + base_b + inner) = o;
      }
    }
  }

  // ---- phase 2: bias precompute, inputs gathered from global (L1/L2) ----
  float4 bgv = *(const float4*)b_gate;
  float4 bdbv = *(const float4*)b_db;
  for (int p = tid; p < KNBR * SUBK; p += 512) {
    int kl = p / SUBK, s = p - kl * SUBK;
    int j = sub_idx[(size_t)(e0 + kl) * SUBK + s];
    sub_lds[p] = (ushortT)j;
    int dk = edge_index[e0 + kl];
    int dj = edge_index[e0 + j];
    float dx = node_trans[dk * 3 + 0] - node_trans[dj * 3 + 0] + EPSC;
    float dy = node_trans[dk * 3 + 1] - node_trans[dj * 3 + 1] + EPSC;
    float dz = node_trans[dk * 3 + 2] - node_trans[dj * 3 + 2] + EPSC;
    float dist = sqrtf(dx * dx + dy * dy + dz * dz);
    int r0 = (int)(dist * INV_MU_STEP + 0.5f);
    int rlo = max(r0 - 4, 0), rhi = min(r0 + 4, 63);
    float a0 = 0.f, a1 = 0.f, a2 = 0.f, a3 = 0.f;
    for (int r = rlo; r <= rhi; ++r) {
      float t = (dist - r * MU_STEP) * INV_SIGMA;
      float e = __expf(-t * t);
      float4 wv = ((const float4*)W_db)[r];
      a0 += e * wv.x; a1 += e * wv.y; a2 += e * wv.z; a3 += e * wv.w;
    }
    float4 gk = *(const float4*)(g + dk * 8);       // g1(dk)
    float4 gj = *(const float4*)(g + dj * 8 + 4);   // g2(dj)
    float g1 = gk.x + gj.x + bgv.x;
    float g2 = gk.y + gj.y + bgv.y;
    float g3 = gk.z + gj.z + bgv.z;
    float g4 = gk.w + gj.w + bgv.w;
    biasb[p * 4 + 0] = f2h((a0 + bdbv.x) / (1.0f + __expf(-g1)));
    biasb[p * 4 + 1] = f2h((a1 + bdbv.y) / (1.0f + __expf(-g2)));
    biasb[p * 4 + 2] = f2h((a2 + bdbv.z) / (1.0f + __expf(-g3)));
    biasb[p * 4 + 3] = f2h((a3 + bdbv.w) / (1.0f + __expf(-g4)));
  }
  __syncthreads();  // barrier 1: kvb + q(updq) + biasb + sub_lds visible

  // ---- phase 3: attention, single pass, packed-f32 math ----
  int row3 = tid >> 3, h = (tid >> 1) & 3, dh = tid & 1;
  int row3c = min(row3, KNBR - 1);
  int hdo = (h * 2 + dh) * 16;
  const char* kvbase = (const char*)kvb;
  f32x2 qv0, qv1, qv2, qv3, qv4, qv5, qv6, qv7;
  {
    const ushortT* qp = updq + row3 * 136 + h * 32 + dh * 16;
    uint4 u0 = *(const uint4*)qp;
    uint4 u1 = *(const uint4*)(qp + 8);
    qv0 = bfpair(u0.x); qv1 = bfpair(u0.y); qv2 = bfpair(u0.z); qv3 = bfpair(u0.w);
    qv4 = bfpair(u1.x); qv5 = bfpair(u1.y); qv6 = bfpair(u1.z); qv7 = bfpair(u1.w);
  }
  float den = 0.f;
  f32x2 va0 = {0.f, 0.f}, va1 = {0.f, 0.f}, va2 = {0.f, 0.f}, va3 = {0.f, 0.f};
  f32x2 va4 = {0.f, 0.f}, va5 = {0.f, 0.f}, va6 = {0.f, 0.f}, va7 = {0.f, 0.f};
#pragma unroll 4
  for (int s = 0; s < SUBK; ++s) {
    int j = sub_lds[row3c * SUBK + s];
    int off = hdo ^ ((j & 7) << 4);
    const char* kr = kvbase + j * 512;
    uint4 k0 = *(const uint4*)(kr + off);
    uint4 k1 = *(const uint4*)(kr + 128 + off);
    f32x2 dacc = qv0 * bfpair(k0.x);
    dacc += qv1 * bfpair(k0.y);
    dacc += qv2 * bfpair(k0.z);
    dacc += qv3 * bfpair(k0.w);
    dacc += qv4 * bfpair(k1.x);
    dacc += qv5 * bfpair(k1.y);
    dacc += qv6 * bfpair(k1.z);
    dacc += qv7 * bfpair(k1.w);
    float dot = dacc.x + dacc.y;
    dot += __shfl_xor(dot, 1);
    float p = __expf(dot + h2f(biasb[(row3c * SUBK + s) * 4 + h]));
    den += p;
    f32x2 pp = {p, p};
    uint4 w0 = *(const uint4*)(kr + 256 + off);
    uint4 w1 = *(const uint4*)(kr + 384 + off);
    va0 += pp * bfpair(w0.x);
    va1 += pp * bfpair(w0.y);
    va2 += pp * bfpair(w0.z);
    va3 += pp * bfpair(w0.w);
    va4 += pp * bfpair(w1.x);
    va5 += pp * bfpair(w1.y);
    va6 += pp * bfpair(w1.z);
    va7 += pp * bfpair(w1.w);
  }
  float inv = 1.0f / den;
  {
    uint4 o;
    o.x = pack2bf(va0.x * inv, va0.y * inv);
    o.y = pack2bf(va1.x * inv, va1.y * inv);
    o.z = pack2bf(va2.x * inv, va2.y * inv);
    o.w = pack2bf(va3.x * inv, va3.y * inv);
    *(uint4*)(updq + row3 * 136 + h * 32 + dh * 16) = o;
    uint4 o2;
    o2.x = pack2bf(va4.x * inv, va4.y * inv);
    o2.y = pack2bf(va5.x * inv, va5.y * inv);
    o2.z = pack2bf(va6.x * inv, va6.y * inv);
    o2.w = pack2bf(va7.x * inv, va7.y * inv);
    *(uint4*)(updq + row3 * 136 + h * 32 + dh * 16 + 8) = o2;
  }
  __syncthreads();  // barrier 2: upd visible

  // ---- phase 4: out projection, 2 tiles/wave x 2 row-sets ----
  bf16x8 af2[2][4];
#pragma unroll
  for (int rs = 0; rs < 2; ++rs) {
    int row = rh * 32 + rs * 16 + lr;
#pragma unroll
    for (int t = 0; t < 4; ++t)
      af2[rs][t] = *(const bf16x8*)(updq + row * 136 + t * 32 + lc * 8);
  }
#pragma unroll
  for (int i = 0; i < 2; ++i) {
    int T = tg * 2 + i;
    bf16x8 bfrag[4];
#pragma unroll
    for (int t = 0; t < 4; ++t)
      bfrag[t] = *(const bf16x8*)(Wp2 + ((T * 4 + t) * 64 + l) * 8);
    int col0 = T * 16 + lc * 4;
    float4 bi = *(const float4*)(bout + col0);
#pragma unroll
    for (int rs = 0; rs < 2; ++rs) {
      f32x4 acc = {0.f, 0.f, 0.f, 0.f};
#pragma unroll
      for (int t = 0; t < 4; ++t)
        acc = __builtin_amdgcn_mfma_f32_16x16x32_bf16(bfrag[t], af2[rs][t], acc, 0, 0, 0);
      int row = rh * 32 + rs * 16 + lr;
      if (row < KNBR) {
        float4 o;
        o.x = acc[0] + bi.x; o.y = acc[1] + bi.y;
        o.z = acc[2] + bi.z; o.w = acc[3] + bi.w;
        *(float4*)(outp + (size_t)(e0 + row) * 128 + col0) = o;
      }
    }
  }
}

extern "C" void kernel_launch(void* const* d_in, const int* in_sizes, int n_in, void* d_out,
                              int out_size, void* d_ws, size_t ws_size, hipStream_t stream) {
  const float* nf  = (const float*)d_in[0];
  const float* nt  = (const float*)d_in[1];
  const float* ef  = (const float*)d_in[2];
  const int*   ei  = (const int*)d_in[3];
  const int*   si  = (const int*)d_in[4];
  const float* Wg  = (const float*)d_in[5];
  const float* bg  = (const float*)d_in[6];
  const float* Wdb = (const float*)d_in[7];
  const float* bdb = (const float*)d_in[8];
  const float* Wqk = (const float*)d_in[9];
  const float* bqk = (const float*)d_in[10];
  const float* Wv  = (const float*)d_in[11];
  const float* bv  = (const float*)d_in[12];
  const float* Wout = (const float*)d_in[13];
  const float* bout = (const float*)d_in[14];
  float* out = (float*)d_out;  // f32 output

  float* g      = (float*)d_ws;                 // 3072 f32
  float* bc     = g + 3072;                     // 384 f32
  ushortT* Wp1  = (ushortT*)(bc + 384);         // 49152 bf16
  ushortT* Wp2  = Wp1 + 49152;                  // 16384 bf16

  prep_kernel<<<dim3(352), dim3(256), 0, stream>>>(nf, Wg, g, Wqk, bqk, Wv, bv, Wout,
                                                   Wp1, Wp2, bc);
  fused_kernel<<<dim3(N_NODES), dim3(512), 0, stream>>>(ef, Wp1, Wp2, bc, bout, g, nt, ei, si,
                                                        Wdb, bdb, bg, out);
}